// Round 12
// baseline (275.342 us; speedup 1.0000x reference)
//
#include <hip/hip_runtime.h>
#include <cstdint>

#define B   64
#define NJ  21
#define CHN 256
#define HW  4096
#define G3  768

typedef _Float16 f16x8 __attribute__((ext_vector_type(8)));
typedef float    f32x4 __attribute__((ext_vector_type(4)));
typedef _Float16 f16x2 __attribute__((ext_vector_type(2)));
typedef __fp16   fp16x2v __attribute__((ext_vector_type(2)));
union PKU { fp16x2v h; unsigned u; };
union HU { unsigned u; f16x2 h; };
union FRU { f16x8 v; unsigned u[4]; };

static __device__ inline unsigned pack_f16(float a, float b){
  HU u; u.h.x = (_Float16)a; u.h.y = (_Float16)b; return u.u;
}

static __device__ inline float fdot2f(unsigned wu, unsigned hu, float acc){
  HU w, h; w.u = wu; h.u = hu;
#if __has_builtin(__builtin_amdgcn_fdot2)
  return __builtin_amdgcn_fdot2(w.h, h.h, acc, false);
#else
  return acc + (float)w.h.x*(float)h.h.x + (float)w.h.y*(float)h.h.y;
#endif
}

// async global->LDS, 16B per lane; dest = lds + lane*16 (HW), src = per-lane address
static __device__ __forceinline__ void gload_lds16(const float* g, float* l){
#if __has_builtin(__builtin_amdgcn_global_load_lds)
  __builtin_amdgcn_global_load_lds((const __attribute__((address_space(1))) void*)g,
                                   (__attribute__((address_space(3))) void*)l, 16, 0, 0);
#else
  int lane = threadIdx.x & 63;
  f32x4 v = *(const f32x4*)g;
  *(f32x4*)((char*)l + lane*16) = v;
#endif
}

// ---------- Laplacian ----------
__global__ __launch_bounds__(64) void k_lap(const float* __restrict__ adj, float* __restrict__ L){
  __shared__ float dinv[NJ];
  int t = threadIdx.x;
  if (t < NJ){
    float s = 0.f;
    for (int j=0;j<NJ;j++) s += adj[t*NJ+j];
    dinv[t] = s > 0.f ? 1.f/sqrtf(s) : 0.f;
  }
  __syncthreads();
  for (int idx=t; idx<NJ*NJ; idx+=64){
    int i = idx/NJ, j = idx%NJ;
    L[idx] = (i==j ? 1.f : 0.f) - dinv[i]*adj[idx]*dinv[j];
  }
}

// ---------- Correlation: MFMA + deep async DMA pipeline (MLP via LDS, not VGPRs) ----------
// grid 1024 = b(64) x kb(8) x nb(2); 512 thr = 8 waves; 80KB LDS -> 2 blocks/CU.
// Each wave: 3 private 2KB F-slots, 3-deep global_load_lds pipeline, vmcnt(4) counted waits.
// Lane's B-frag is its own data: DMA lane-linear, read back at slot+lane*16 (conflict-free).
__global__ __launch_bounds__(512,4) void k_corr7(const float* __restrict__ T,
    const float* __restrict__ F, _Float16* __restrict__ P){
  int bid = blockIdx.x;
  int nb = bid & 1, kb = (bid>>1)&7, b = bid>>4;
  int t = threadIdx.x;
  int w = t>>6, l = t&63;
  __shared__ __align__(16) unsigned short Tl[32*512];   // 32 KB f16, XOR-swizzled
  __shared__ __align__(16) float Fl[8][3][512];         // 48 KB: 8 waves x 3 slots x 2KB

  // zero T pad rows 21..31
  for (int i=t; i<2816; i+=512){
    int r = 21 + i/256, wo = i%256;
    *(unsigned*)((char*)Tl + (r*1024 + ((wo*4) ^ ((r&7)<<4)))) = 0u;
  }
  // stage T rows 0..20 (f32 -> f16)
  {
    const float2* Tp = (const float2*)(T + (size_t)b*NJ*HW + (size_t)kb*512);
    for (int i=t; i<21*256; i+=512){
      int r = i>>8, pr = i&255;
      float2 v = Tp[(size_t)r*2048 + pr];
      PKU pk; pk.h = __builtin_amdgcn_cvt_pkrtz(v.x, v.y);
      *(unsigned*)((char*)Tl + (r*1024 + ((pr*4) ^ ((r&7)<<4)))) = pk.u;
    }
  }
  __syncthreads();

  int cl = l & 15, kg = l >> 4;
  const float* gsrc = F + ((size_t)b*CHN + nb*128 + w*16 + cl)*HW + (size_t)kb*512 + kg*8;
  float* slotbase = &Fl[w][0][0];

  f32x4 acc0 = {0.f,0.f,0.f,0.f}, acc1 = {0.f,0.f,0.f,0.f};
  int r = cl;
  int swz = (r&7)<<4;
  const char* TlB = (const char*)Tl;

  // prologue: chunks 0,1 -> slots 0,1 (4 DMA instr in flight)
  gload_lds16(gsrc + 0*32,     slotbase);
  gload_lds16(gsrc + 0*32 + 4, slotbase + 256);
  gload_lds16(gsrc + 1*32,     slotbase + 512);
  gload_lds16(gsrc + 1*32 + 4, slotbase + 512 + 256);

  #pragma unroll
  for (int c=0; c<16; ++c){
    int cc = (c+2 < 16) ? (c+2) : 15;          // clamp: redundant re-load, keeps vmcnt uniform
    float* lpn = slotbase + ((c+2)%3)*512;
    gload_lds16(gsrc + cc*32,     lpn);
    gload_lds16(gsrc + cc*32 + 4, lpn + 256);
    asm volatile("s_waitcnt vmcnt(4)" ::: "memory");   // chunk c's 2 DMAs retired
    __builtin_amdgcn_sched_barrier(0);
    const char* sp = (const char*)(slotbase + (c%3)*512);
    f32x4 v0 = *(const f32x4*)(sp + l*16);
    f32x4 v1 = *(const f32x4*)(sp + 1024 + l*16);
    FRU bf;
    bf.u[0] = pack_f16(v0[0], v0[1]);
    bf.u[1] = pack_f16(v0[2], v0[3]);
    bf.u[2] = pack_f16(v1[0], v1[1]);
    bf.u[3] = pack_f16(v1[2], v1[3]);
    int kbyte = c*64 + kg*16;
    f16x8 a0 = *(const f16x8*)(TlB + (r*1024      + (kbyte ^ swz)));
    f16x8 a1 = *(const f16x8*)(TlB + ((r+16)*1024 + (kbyte ^ swz)));
    acc0 = __builtin_amdgcn_mfma_f32_16x16x32_f16(a0, bf.v, acc0, 0, 0, 0);
    acc1 = __builtin_amdgcn_mfma_f32_16x16x32_f16(a1, bf.v, acc1, 0, 0, 0);
    __builtin_amdgcn_sched_barrier(0);          // pin iteration region (slot-reuse safety)
  }

  int cbase = nb*128 + w*16 + (l&15);
  #pragma unroll
  for (int i=0;i<4;i++){
    int row0 = (l>>4)*4 + i;
    if (row0 < 21)
      P[(((size_t)kb*64 + b)*21 + row0)*256 + cbase] = (_Float16)acc0[i];
    int row1 = row0 + 16;
    if (row1 < 21)
      P[(((size_t)kb*64 + b)*21 + row1)*256 + cbase] = (_Float16)acc1[i];
  }
}

// ---------- BN stats per joint; reduces the 8 k-partials into f32 q ----------
__global__ __launch_bounds__(256) void k_stats(const _Float16* __restrict__ P,
    float* __restrict__ q, float* __restrict__ stats){
  int j = blockIdx.x, t = threadIdx.x;
  const size_t KSTRIDE = (size_t)64*21*256;
  float s = 0.f, ss = 0.f;
  for (int b=0;b<B;b++){
    size_t i0 = ((size_t)b*21 + j)*256 + t;
    float v = 0.f;
    #pragma unroll
    for (int k=0;k<8;k++) v += (float)P[k*KSTRIDE + i0];
    q[((size_t)b*NJ + j)*CHN + t] = v;
    s += v; ss += v*v;
  }
  #pragma unroll
  for (int o=32;o>0;o>>=1){ s += __shfl_down(s,o); ss += __shfl_down(ss,o); }
  __shared__ float sb[4], ssb[4];
  int wid = t>>6;
  if ((t&63)==0){ sb[wid]=s; ssb[wid]=ss; }
  __syncthreads();
  if (t==0){
    float S  = sb[0]+sb[1]+sb[2]+sb[3];
    float SS = ssb[0]+ssb[1]+ssb[2]+ssb[3];
    float mean = S * (1.f/16384.f);
    float var  = SS * (1.f/16384.f) - mean*mean;
    stats[j]      = mean;
    stats[NJ + j] = 1.f/sqrtf(var + 1e-5f);
  }
}

// ---------- BN apply + LeakyReLU + xg = xn @ wx + bx ----------
__global__ __launch_bounds__(256) void k_xg(const float* __restrict__ q,
    const float* __restrict__ stats, const float* __restrict__ gamma, const float* __restrict__ beta,
    const float* __restrict__ wx, const float* __restrict__ bx, float* __restrict__ xg){
  int b = blockIdx.x/3, sl = blockIdx.x%3;
  int t = threadIdx.x;
  int col = sl*256 + t;
  __shared__ float xn[NJ][CHN];
  for (int idx=t; idx<NJ*CHN; idx+=256){
    int j = idx >> 8;
    float v = (q[(size_t)b*NJ*CHN + idx] - stats[j]) * stats[NJ+j];
    v = v * gamma[j] + beta[j];
    xn[j][idx & 255] = v > 0.f ? v : 0.1f*v;
  }
  __syncthreads();
  float acc[NJ];
  #pragma unroll
  for (int j=0;j<NJ;j++) acc[j]=0.f;
  for (int c=0;c<CHN;c++){
    float wv = wx[(size_t)c*G3 + col];
    #pragma unroll
    for (int j=0;j<NJ;j++) acc[j] += xn[j][c]*wv;
  }
  float bv = bx[col];
  #pragma unroll
  for (int j=0;j<NJ;j++) xg[((size_t)b*NJ+j)*G3 + col] = acc[j] + bv;
}

// ---------- pack wh to f16 pairs, layout [c2][col] ----------
__global__ __launch_bounds__(256) void k_pack(const float* __restrict__ wh, unsigned* __restrict__ whp){
  int idx = blockIdx.x*256 + threadIdx.x;
  int c2 = idx / G3, col = idx % G3;
  float w0 = wh[(size_t)(2*c2)*G3 + col];
  float w1 = wh[(size_t)(2*c2+1)*G3 + col];
  whp[idx] = pack_f16(w0, w1);
}

// ---------- GRU (UNCHANGED): hybrid weights, 64 VGPR-resident + 64 streamed ----------
__global__ __launch_bounds__(768,3) void k_gru(const unsigned* __restrict__ whp,
    const float* __restrict__ bh, const float* __restrict__ xg, float* __restrict__ gout){
  int b = blockIdx.x;
  int col = threadIdx.x;
  int l = col & 63;
  __shared__ float hf[256];
  __shared__ float lr[256], lz[256];
  unsigned wr[64];
  #pragma unroll
  for (int i=0;i<64;i++) wr[i] = whp[i*G3 + col];
  const unsigned* wsp = whp + 64*G3 + col;
  float bhv = bh[col];
  if (col < 256) hf[col] = 0.f;
  unsigned hv0 = 0u, hv1 = 0u;
  float xv_next = xg[((size_t)b*NJ + 0)*G3 + col];
  __syncthreads();
  for (int step=0; step<NJ; ++step){
    float xvc = xv_next;
    if (step < NJ-1) xv_next = xg[((size_t)b*NJ + step+1)*G3 + col];
    float a0 = 0.f, a1 = 0.f;
    #pragma unroll
    for (int i=0;i<64;i++)
      a1 = fdot2f(wsp[(size_t)i*G3], __builtin_amdgcn_readlane(hv1, i), a1);
    #pragma unroll
    for (int i=0;i<64;i++)
      a0 = fdot2f(wr[i], __builtin_amdgcn_readlane(hv0, i), a0);
    float a = a0 + a1 + bhv;
    if (col < 256)      lr[col]     = 1.f/(1.f+__expf(-(xvc + a)));
    else if (col < 512) lz[col-256] = 1.f/(1.f+__expf(-(xvc + a)));
    __syncthreads();
    if (col >= 512){
      int i = col - 512;
      float nv = tanhf(xvc + lr[i]*a);
      float z  = lz[i];
      float hnew = (1.f - z)*nv + z*hf[i];
      gout[((size_t)b*NJ + step)*CHN + i] = hnew;
      hf[i] = hnew;
    }
    __syncthreads();
    float2 p0 = *(const float2*)&hf[2*l];
    float2 p1 = *(const float2*)&hf[128 + 2*l];
    hv0 = pack_f16(p0.x, p0.y);
    hv1 = pack_f16(p1.x, p1.y);
  }
}

// ---------- ChebConv K=2 + bias + ReLU ----------
__global__ __launch_bounds__(256) void k_cheb(const float* __restrict__ xin,
    const float* __restrict__ Lm, const float* __restrict__ W,
    const float* __restrict__ bvec, float* __restrict__ out){
  int b = blockIdx.x >> 2, oq = blockIdx.x & 3;
  int t = threadIdx.x;
  int ol = t & 63, ck = t >> 6;
  __shared__ float xs[NJ][CHN];
  __shared__ float lx[NJ][CHN];
  __shared__ float part[4][64][NJ];
  for (int idx=t; idx<NJ*CHN; idx+=256) xs[idx>>8][idx&255] = xin[(size_t)b*NJ*CHN + idx];
  __syncthreads();
  for (int idx=t; idx<NJ*CHN; idx+=256){
    int j = idx>>8, c = idx&255;
    float sacc = 0.f;
    #pragma unroll
    for (int m=0;m<NJ;m++) sacc += Lm[j*NJ+m]*xs[m][c];
    lx[j][c] = sacc;
  }
  __syncthreads();
  int o = oq*64 + ol;
  float acc[NJ];
  #pragma unroll
  for (int j=0;j<NJ;j++) acc[j]=0.f;
  const float* W0 = W;
  const float* W1 = W + CHN*CHN;
  for (int cc=0; cc<64; ++cc){
    int c = ck*64 + cc;
    float w0 = W0[(size_t)c*CHN + o];
    float w1 = W1[(size_t)c*CHN + o];
    #pragma unroll
    for (int j=0;j<NJ;j++){ acc[j] += xs[j][c]*w0; acc[j] += lx[j][c]*w1; }
  }
  #pragma unroll
  for (int j=0;j<NJ;j++) part[ck][ol][j] = acc[j];
  __syncthreads();
  for (int idx=t; idx<64*NJ; idx+=256){
    int o2 = idx & 63, j = idx >> 6;
    float s2 = part[0][o2][j]+part[1][o2][j]+part[2][o2][j]+part[3][o2][j] + bvec[oq*64+o2];
    s2 = s2 > 0.f ? s2 : 0.f;
    out[(size_t)b*NJ*CHN + j*CHN + oq*64 + o2] = s2;
  }
}

// ---------- Output head ----------
__global__ __launch_bounds__(64) void k_out(const float* __restrict__ gq, const float* __restrict__ h2,
    const float* __restrict__ Lm, const float* __restrict__ W, const float* __restrict__ bvec,
    float* __restrict__ out){
  int b = blockIdx.x, t = threadIdx.x;
  __shared__ float xs[NJ][CHN];
  __shared__ float lx[NJ][CHN];
  for (int idx=t; idx<NJ*CHN; idx+=64)
    xs[idx>>8][idx&255] = gq[(size_t)b*NJ*CHN+idx] + h2[(size_t)b*NJ*CHN+idx];
  __syncthreads();
  for (int idx=t; idx<NJ*CHN; idx+=64){
    int j = idx>>8, c = idx&255;
    float s = 0.f;
    #pragma unroll
    for (int m=0;m<NJ;m++) s += Lm[j*NJ+m]*xs[m][c];
    lx[j][c] = s;
  }
  __syncthreads();
  if (t < 63){
    int j = t/3, o = t%3;
    float acc = bvec[o];
    const float* W0 = W;
    const float* W1 = W + CHN*3;
    for (int c=0;c<CHN;c++){
      acc += xs[j][c]*W0[c*3+o];
      acc += lx[j][c]*W1[c*3+o];
    }
    out[(size_t)b*63 + t] = acc;
  }
}

extern "C" void kernel_launch(void* const* d_in, const int* in_sizes, int n_in,
                              void* d_out, int out_size, void* d_ws, size_t ws_size,
                              hipStream_t stream){
  const float* feat  = (const float*)d_in[0];
  const float* targ  = (const float*)d_in[1];
  const float* adj   = (const float*)d_in[2];
  const float* gamma = (const float*)d_in[3];
  const float* beta  = (const float*)d_in[4];
  const float* wx    = (const float*)d_in[5];
  const float* wh    = (const float*)d_in[6];
  const float* bx    = (const float*)d_in[7];
  const float* bh    = (const float*)d_in[8];
  const float* wg1   = (const float*)d_in[9];
  const float* bg1   = (const float*)d_in[10];
  const float* wg2   = (const float*)d_in[11];
  const float* bg2   = (const float*)d_in[12];
  const float* wout  = (const float*)d_in[13];
  const float* bout  = (const float*)d_in[14];

  float* ws   = (float*)d_ws;
  float* q     = ws + 0;                 // 344064
  float* stats = ws + 400000;            // 64
  float* Lw    = ws + 400128;            // 441
  float* xgw   = ws + 500000;            // 1032192
  float* gout  = ws + 1600000;           // 344064
  float* h1    = ws + 2000000;           // 344064
  float* h2b   = ws + 2400000;           // 344064
  unsigned* whp = (unsigned*)(ws + 2800000);    // 98304
  _Float16* P  = (_Float16*)(ws + 3000000);     // 8*64*21*256 = 2752512 halves

  k_lap  <<<1,    64, 0, stream>>>(adj, Lw);
  k_pack <<<384, 256, 0, stream>>>(wh, whp);
  k_corr7<<<1024,512, 0, stream>>>(targ, feat, P);
  k_stats<<<21,  256, 0, stream>>>(P, q, stats);
  k_xg   <<<192, 256, 0, stream>>>(q, stats, gamma, beta, wx, bx, xgw);
  k_gru  <<<64,  768, 0, stream>>>(whp, bh, xgw, gout);
  k_cheb <<<256, 256, 0, stream>>>(gout, Lw, wg1, bg1, h1);
  k_cheb <<<256, 256, 0, stream>>>(h1,   Lw, wg2, bg2, h2b);
  k_out  <<<64,   64, 0, stream>>>(gout, h2b, Lw, wout, bout, (float*)d_out);
}